// Round 1
// baseline (620.722 us; speedup 1.0000x reference)
//
#include <hip/hip_runtime.h>

typedef unsigned long long u64;
typedef unsigned short u16;

#define NN 4096
#define NCH 64          // u64 chunks per bit-row
#define NSUP 6

// ============================ init ============================
__global__ void k_init(float* out, int out_n, int* comp, int* parent,
                       u64* comp_best, int* ncomp, int* mstcnt) {
  int t = blockIdx.x * blockDim.x + threadIdx.x;
  int nt = gridDim.x * blockDim.x;
  for (int v = t; v < NN; v += nt) { comp[v] = v; parent[v] = v; comp_best[v] = 0ull; }
  for (int i = t; i < out_n; i += nt) out[i] = 0.0f;
  if (t == 0) { *ncomp = NN; *mstcnt = 0; }
}

// ==================== pack A rows into bits ====================
__global__ void k_pack(const float* __restrict__ A, u64* __restrict__ bits) {
  int g = blockIdx.x * blockDim.x + threadIdx.x;
  if (g >= NN * NCH) return;
  int row = g >> 6, ch = g & 63;
  const float4* p = reinterpret_cast<const float4*>(A + (size_t)row * NN + (size_t)ch * 64);
  u64 b = 0;
#pragma unroll
  for (int q = 0; q < 16; ++q) {
    float4 v = p[q];
    b |= (u64)(v.x > 0.0f) << (q * 4 + 0);
    b |= (u64)(v.y > 0.0f) << (q * 4 + 1);
    b |= (u64)(v.z > 0.0f) << (q * 4 + 2);
    b |= (u64)(v.w > 0.0f) << (q * 4 + 3);
  }
  bits[g] = b;
}

// ============================ degrees ============================
__global__ void k_deg(const u64* __restrict__ bits, u16* __restrict__ deg) {
  int v = blockIdx.x * blockDim.x + threadIdx.x;
  if (v >= NN) return;
  const u64* r = bits + (size_t)v * NCH;
  int d = 0;
#pragma unroll
  for (int c = 0; c < NCH; ++c) d += __popcll(r[c]);
  deg[v] = (u16)d;
}

// ========== inter[i][j] = |N(i) & N(j)| via popcount GEMM ==========
// 64x64-pair tiles, 256 threads, thread computes 4x4 pairs.
// LDS rows stored in 16B units, XOR-swizzled by (row>>2)&7 to avoid conflicts.
__global__ __launch_bounds__(256) void k_inter(const u64* __restrict__ bits,
                                               u16* __restrict__ inter) {
  __shared__ ulonglong2 Li[64 * 32];   // 32 KiB
  __shared__ ulonglong2 Lj[64 * 32];   // 32 KiB
  int bx = blockIdx.x & 63, by = blockIdx.x >> 6;
  int i0 = by * 64, j0 = bx * 64;
  int t = threadIdx.x;
  {
    int r = t >> 2, q = t & 3;
    int sw = (r >> 2) & 7;
    const ulonglong2* gi = reinterpret_cast<const ulonglong2*>(bits + (size_t)(i0 + r) * NCH);
    const ulonglong2* gj = reinterpret_cast<const ulonglong2*>(bits + (size_t)(j0 + r) * NCH);
#pragma unroll
    for (int s = 0; s < 8; ++s) {
      int cu = q * 8 + s;
      Li[r * 32 + (cu ^ sw)] = gi[cu];
      Lj[r * 32 + (cu ^ sw)] = gj[cu];
    }
  }
  __syncthreads();
  int tx = t & 15, ty = t >> 4;
  int swi = ty & 7, swj = tx & 7;
  int acc[4][4] = {};
  for (int cu = 0; cu < 32; ++cu) {
    ulonglong2 av[4], bv[4];
#pragma unroll
    for (int a = 0; a < 4; ++a) av[a] = Li[(ty * 4 + a) * 32 + (cu ^ swi)];
#pragma unroll
    for (int b = 0; b < 4; ++b) bv[b] = Lj[(tx * 4 + b) * 32 + (cu ^ swj)];
#pragma unroll
    for (int a = 0; a < 4; ++a)
#pragma unroll
      for (int b = 0; b < 4; ++b)
        acc[a][b] += __popcll(av[a].x & bv[b].x) + __popcll(av[a].y & bv[b].y);
  }
#pragma unroll
  for (int a = 0; a < 4; ++a) {
    int i = i0 + ty * 4 + a;
    ushort4 wv;
    wv.x = (u16)acc[a][0]; wv.y = (u16)acc[a][1];
    wv.z = (u16)acc[a][2]; wv.w = (u16)acc[a][3];
    *reinterpret_cast<ushort4*>(inter + (size_t)i * NN + j0 + tx * 4) = wv;
  }
}

// ===== Boruvka phase A: per-node best outgoing edge (one block/node) =====
// node-local order: (sim desc, partner u asc)  ==  (sim desc, pair-index asc)
__global__ __launch_bounds__(256) void k_scan(const u16* __restrict__ inter,
                                              const u16* __restrict__ deg,
                                              const int* __restrict__ comp,
                                              const int* __restrict__ ncomp,
                                              u64* __restrict__ nkey,
                                              int* __restrict__ nu) {
  if (*ncomp <= 1) return;
  int v = blockIdx.x;
  int t = threadIdx.x;
  int cv = comp[v];
  int dv = (int)deg[v];
  const u16* row = inter + (size_t)v * NN;
  u64 best = 0; int bu = -1;
  for (int u = t; u < NN; u += 256) {
    if (comp[u] == cv) continue;
    int iv = (int)row[u];
    int un = dv + (int)deg[u] - iv;
    float s = (un > 0) ? ((float)iv / (float)un) : 0.0f;   // matches numpy fp32 division exactly
    u64 k = ((u64)__float_as_uint(s) << 32) | (u64)(0xFFFFFFFFu - (unsigned)u);
    if (k > best) { best = k; bu = u; }
  }
  __shared__ u64 rk[256];
  __shared__ int ru[256];
  rk[t] = best; ru[t] = bu;
  __syncthreads();
  for (int s = 128; s > 0; s >>= 1) {
    if (t < s && rk[t + s] > rk[t]) { rk[t] = rk[t + s]; ru[t] = ru[t + s]; }
    __syncthreads();
  }
  if (t == 0) {
    int u = ru[0];
    u64 pk = 0;
    if (u >= 0) {
      unsigned simb = (unsigned)(rk[0] >> 32);
      int i = v < u ? v : u, j = v < u ? u : v;
      unsigned idx = (unsigned)i * (unsigned)(2 * NN - i - 1) / 2u + (unsigned)(j - i - 1);
      pk = ((u64)simb << 24) | (u64)(0xFFFFFFu - idx);   // comp-level comparable pair key
    }
    nkey[v] = pk; nu[v] = u;
  }
}

// ===== Boruvka phase B: component-best, hook, 2-cycle break, jump =====
__global__ __launch_bounds__(1024) void k_merge(const u64* __restrict__ nkey,
                                                const int* __restrict__ nu,
                                                int* comp, int* parent, u64* comp_best,
                                                int* ncomp, int* mstcnt,
                                                u64* mkey, int* mi, int* mj) {
  if (*ncomp <= 1) return;
  int t = threadIdx.x;
  for (int v = t; v < NN; v += 1024) atomicMax(&comp_best[comp[v]], nkey[v]);
  __syncthreads();
  for (int v = t; v < NN; v += 1024) {
    u64 k = nkey[v];
    int c = comp[v];
    u64 cb = atomicAdd(&comp_best[c], 0ull);        // coherent read
    if (k != 0ull && k == cb) {
      int u = nu[v];
      int cu = comp[u];
      u64 cbu = atomicAdd(&comp_best[cu], 0ull);
      bool mutual = (cbu == k);
      if (!mutual || v < u) {
        int slot = atomicAdd(mstcnt, 1);
        mkey[slot] = k; mi[slot] = v; mj[slot] = u;
      }
      parent[c] = cu;                                // one winner per component
    }
  }
  __syncthreads();
  for (int c = t; c < NN; c += 1024) {               // break mutual 2-cycles: keep smaller root
    int pc = parent[c];
    if (parent[pc] == c && c < pc) parent[c] = c;
  }
  __syncthreads();
  for (int it = 0; it < 13; ++it) {                  // pointer jumping
    for (int c = t; c < NN; c += 1024) parent[c] = parent[parent[c]];
    __syncthreads();
  }
  for (int v = t; v < NN; v += 1024) comp[v] = parent[comp[v]];
  __syncthreads();
  __shared__ unsigned char mk_s[NN];
  __shared__ int cnt_s;
  for (int c = t; c < NN; c += 1024) mk_s[c] = 0;
  if (t == 0) cnt_s = 0;
  __syncthreads();
  for (int v = t; v < NN; v += 1024) mk_s[comp[v]] = 1;
  __syncthreads();
  int lc = 0;
  for (int c = t; c < NN; c += 1024) lc += mk_s[c];
  atomicAdd(&cnt_s, lc);
  __syncthreads();
  if (t == 0) *ncomp = cnt_s;
  for (int c = t; c < NN; c += 1024) { parent[c] = c; comp_best[c] = 0ull; }
}

// ===== finalize: drop 5 smallest MST edges, CC, labels, P =====
__global__ __launch_bounds__(1024) void k_finalize(u64* mkey, const int* __restrict__ mi,
                                                   const int* __restrict__ mj,
                                                   const int* __restrict__ mstcnt,
                                                   int* labels_g, float* invs_g, float* out) {
  __shared__ int p[NN];        // 16 KiB
  __shared__ int rr[NN];       // 16 KiB (root -> rank LUT)
  __shared__ u64 rk[1024];
  __shared__ int rs[1024];
  __shared__ int roots[16];
  __shared__ int rcnt;
  __shared__ int szs[8];
  __shared__ float ivs[8];
  __shared__ int changed;
  int t = threadIdx.x;
  int nm = *mstcnt;            // 4095
  for (int v = t; v < NN; v += 1024) p[v] = v;
  // remove the 5 smallest edges under (sim asc, pair-idx desc)  == 5 smallest keys
  for (int pass = 0; pass < NSUP - 1; ++pass) {
    u64 bk = ~0ull; int bs = -1;
    for (int e = t; e < nm; e += 1024) { u64 k = mkey[e]; if (k < bk) { bk = k; bs = e; } }
    rk[t] = bk; rs[t] = bs;
    __syncthreads();
    for (int s = 512; s > 0; s >>= 1) {
      if (t < s && rk[t + s] < rk[t]) { rk[t] = rk[t + s]; rs[t] = rs[t + s]; }
      __syncthreads();
    }
    if (t == 0) mkey[rs[0]] = ~0ull;   // mark removed
    __syncthreads();
  }
  // connected components over kept edges (min-label hook + jump)
  for (int round = 0; round < 64; ++round) {
    if (t == 0) changed = 0;
    __syncthreads();
    for (int e = t; e < nm; e += 1024) {
      if (mkey[e] == ~0ull) continue;
      int a = p[mi[e]], b = p[mj[e]];
      if (a == b) continue;
      int m = a < b ? a : b, M = a < b ? b : a;
      int old = atomicMin(&p[M], m);
      if (old > m) changed = 1;
    }
    __syncthreads();
    for (int rep = 0; rep < 3; ++rep) {
      for (int v = t; v < NN; v += 1024) p[v] = p[p[v]];
      __syncthreads();
    }
    int ch = changed;
    __syncthreads();
    if (!ch) break;
  }
  for (int rep = 0; rep < 13; ++rep) {   // full compression -> p[v] = component min index
    for (int v = t; v < NN; v += 1024) p[v] = p[p[v]];
    __syncthreads();
  }
  if (t == 0) rcnt = 0;
  __syncthreads();
  for (int v = t; v < NN; v += 1024)
    if (p[v] == v) { int s = atomicAdd(&rcnt, 1); if (s < 16) roots[s] = v; }
  __syncthreads();
  if (t == 0) {                           // sort roots asc -> first-occurrence label order
    int c = rcnt > 16 ? 16 : rcnt;
    for (int a = 1; a < c; ++a) {
      int x = roots[a]; int b = a - 1;
      while (b >= 0 && roots[b] > x) { roots[b + 1] = roots[b]; --b; }
      roots[b + 1] = x;
    }
  }
  if (t < 8) szs[t] = 0;
  __syncthreads();
  if (t < rcnt && t < 16) rr[roots[t]] = t;
  __syncthreads();
  for (int v = t; v < NN; v += 1024) {
    int lab = rr[p[v]];
    labels_g[v] = lab;
    atomicAdd(&szs[lab], 1);
  }
  __syncthreads();
  if (t < rcnt && t < 8) {
    float iv = 1.0f / sqrtf((float)szs[t] + 1e-10f);   // bit-matches reference P entries
    ivs[t] = iv; invs_g[t] = iv;
  }
  __syncthreads();
  for (int v = t; v < NN; v += 1024) {                 // P at out+1572, row-major [4096][6]
    int lab = rr[p[v]];
    float* base = out + 1572 + v * 6;
#pragma unroll
    for (int b = 0; b < 6; ++b) base[b] = (b == lab) ? ivs[lab] : 0.0f;
  }
}

// ===== X_coarse = P^T X : label-indexed column sums =====
__global__ __launch_bounds__(256) void k_xcoarse(const float* __restrict__ X,
                                                 const int* __restrict__ labels,
                                                 const float* __restrict__ invs, float* out) {
  __shared__ float acc[6][256];
  __shared__ int labs[64];
  __shared__ float ivl[64];
  int t = threadIdx.x;
#pragma unroll
  for (int m = 0; m < 6; ++m) acc[m][t] = 0.0f;
  if (t < 64) { int v = blockIdx.x * 64 + t; int l = labels[v]; labs[t] = l; ivl[t] = invs[l]; }
  __syncthreads();
  int v0 = blockIdx.x * 64;
  for (int r = 0; r < 64; ++r) {
    float x = X[(size_t)(v0 + r) * 256 + t];
    acc[labs[r]][t] += ivl[r] * x;
  }
  __syncthreads();
#pragma unroll
  for (int m = 0; m < 6; ++m) atomicAdd(&out[m * 256 + t], acc[m][t]);
}

// ===== A_coarse = P^T A P : per-row neighbor-label counts from bit rows =====
__global__ __launch_bounds__(256) void k_acoarse(const u64* __restrict__ bits,
                                                 const int* __restrict__ labels,
                                                 const float* __restrict__ invs, float* out) {
  __shared__ unsigned char labs[NN];   // 4 KiB
  __shared__ float accA[36];
  __shared__ float ivs[8];
  int t = threadIdx.x;
  for (int v = t; v < NN; v += 256) labs[v] = (unsigned char)labels[v];
  if (t < 36) accA[t] = 0.0f;
  if (t < 6) ivs[t] = invs[t];
  __syncthreads();
  int i = blockIdx.x * 256 + t;
  u64 cnt = 0;   // six 10-bit counters
  const u64* row = bits + (size_t)i * NCH;
  for (int c = 0; c < NCH; ++c) {
    u64 w = row[c];
    while (w) {
      int j = (c << 6) + __builtin_ctzll(w);
      w &= w - 1;
      cnt += 1ull << (labs[j] * 10);
    }
  }
  int li = labs[i];
  float fi = ivs[li];
#pragma unroll
  for (int b = 0; b < 6; ++b) {
    float cb = (float)((cnt >> (b * 10)) & 1023ull);
    if (cb != 0.0f) atomicAdd(&accA[li * 6 + b], fi * ivs[b] * cb);
  }
  __syncthreads();
  if (t < 36) atomicAdd(&out[1536 + t], accA[t]);
}

// ============================ launch ============================
extern "C" void kernel_launch(void* const* d_in, const int* in_sizes, int n_in,
                              void* d_out, int out_size, void* d_ws, size_t ws_size,
                              hipStream_t stream) {
  const float* X = (const float*)d_in[0];
  const float* A = (const float*)d_in[1];
  float* out = (float*)d_out;

  char* wp = (char*)d_ws;
  size_t off = 0;
#define WALLOC(ty, name, count) \
  ty* name = (ty*)(wp + off);   \
  off += (((size_t)(count) * sizeof(ty)) + 255) & ~(size_t)255;
  WALLOC(u64, bits, (size_t)NN * NCH)      // 2 MiB
  WALLOC(u16, inter, (size_t)NN * NN)      // 32 MiB
  WALLOC(u16, deg, NN)
  WALLOC(int, comp, NN)
  WALLOC(u64, nkey, NN)
  WALLOC(int, nu, NN)
  WALLOC(u64, comp_best, NN)
  WALLOC(int, parent, NN)
  WALLOC(u64, mkey, 4352)
  WALLOC(int, mi, 4352)
  WALLOC(int, mj, 4352)
  WALLOC(int, labels, NN)
  WALLOC(float, invs, 8)
  WALLOC(int, ncomp, 1)
  WALLOC(int, mstcnt, 1)
#undef WALLOC
  if (off > ws_size) return;   // workspace too small: leave output zeroed (clean fail)

  k_init<<<64, 256, 0, stream>>>(out, out_size, comp, parent, comp_best, ncomp, mstcnt);
  k_pack<<<(NN * NCH) / 256, 256, 0, stream>>>(A, bits);
  k_deg<<<NN / 256, 256, 0, stream>>>(bits, deg);
  k_inter<<<4096, 256, 0, stream>>>(bits, inter);
  for (int ph = 0; ph < 12; ++ph) {
    k_scan<<<NN, 256, 0, stream>>>(inter, deg, comp, ncomp, nkey, nu);
    k_merge<<<1, 1024, 0, stream>>>(nkey, nu, comp, parent, comp_best, ncomp, mstcnt,
                                    mkey, mi, mj);
  }
  k_finalize<<<1, 1024, 0, stream>>>(mkey, mi, mj, mstcnt, labels, invs, out);
  k_xcoarse<<<64, 256, 0, stream>>>(X, labels, invs, out);
  k_acoarse<<<16, 256, 0, stream>>>(bits, labels, invs, out);
}

// Round 2
// 426.644 us; speedup vs baseline: 1.4549x; 1.4549x over previous
//
#include <hip/hip_runtime.h>

typedef unsigned long long u64;
typedef unsigned short u16;

#define NN 4096
#define NCH 64          // u64 chunks per bit-row
#define NSUP 6

// ============================ init ============================
__global__ void k_init(float* out, int out_n, int* comp, int* ncomp, int* mstcnt) {
  int t = blockIdx.x * blockDim.x + threadIdx.x;
  int nt = gridDim.x * blockDim.x;
  for (int v = t; v < NN; v += nt) comp[v] = v;
  for (int i = t; i < out_n; i += nt) out[i] = 0.0f;
  if (t == 0) { *ncomp = NN; *mstcnt = 0; }
}

// ==================== pack A rows into bits ====================
__global__ void k_pack(const float* __restrict__ A, u64* __restrict__ bits) {
  int g = blockIdx.x * blockDim.x + threadIdx.x;
  if (g >= NN * NCH) return;
  int row = g >> 6, ch = g & 63;
  const float4* p = reinterpret_cast<const float4*>(A + (size_t)row * NN + (size_t)ch * 64);
  u64 b = 0;
#pragma unroll
  for (int q = 0; q < 16; ++q) {
    float4 v = p[q];
    b |= (u64)(v.x > 0.0f) << (q * 4 + 0);
    b |= (u64)(v.y > 0.0f) << (q * 4 + 1);
    b |= (u64)(v.z > 0.0f) << (q * 4 + 2);
    b |= (u64)(v.w > 0.0f) << (q * 4 + 3);
  }
  bits[g] = b;
}

// ============================ degrees ============================
__global__ void k_deg(const u64* __restrict__ bits, u16* __restrict__ deg) {
  int v = blockIdx.x * blockDim.x + threadIdx.x;
  if (v >= NN) return;
  const u64* r = bits + (size_t)v * NCH;
  int d = 0;
#pragma unroll
  for (int c = 0; c < NCH; ++c) d += __popcll(r[c]);
  deg[v] = (u16)d;
}

// ========== inter[i][j] = |N(i) & N(j)| via popcount GEMM ==========
// SYMMETRIC: only blocks with by<=bx compute; mirror tile written transposed.
__global__ __launch_bounds__(256) void k_inter(const u64* __restrict__ bits,
                                               u16* __restrict__ inter) {
  int bx = blockIdx.x & 63, by = blockIdx.x >> 6;
  if (by > bx) return;                 // lower-triangle blocks skipped
  __shared__ ulonglong2 Li[64 * 32];   // 32 KiB
  __shared__ ulonglong2 Lj[64 * 32];   // 32 KiB
  int i0 = by * 64, j0 = bx * 64;
  int t = threadIdx.x;
  {
    int r = t >> 2, q = t & 3;
    int sw = (r >> 2) & 7;
    const ulonglong2* gi = reinterpret_cast<const ulonglong2*>(bits + (size_t)(i0 + r) * NCH);
    const ulonglong2* gj = reinterpret_cast<const ulonglong2*>(bits + (size_t)(j0 + r) * NCH);
#pragma unroll
    for (int s = 0; s < 8; ++s) {
      int cu = q * 8 + s;
      Li[r * 32 + (cu ^ sw)] = gi[cu];
      Lj[r * 32 + (cu ^ sw)] = gj[cu];
    }
  }
  __syncthreads();
  int tx = t & 15, ty = t >> 4;
  int swi = ty & 7, swj = tx & 7;
  int acc[4][4] = {};
  for (int cu = 0; cu < 32; ++cu) {
    ulonglong2 av[4], bv[4];
#pragma unroll
    for (int a = 0; a < 4; ++a) av[a] = Li[(ty * 4 + a) * 32 + (cu ^ swi)];
#pragma unroll
    for (int b = 0; b < 4; ++b) bv[b] = Lj[(tx * 4 + b) * 32 + (cu ^ swj)];
#pragma unroll
    for (int a = 0; a < 4; ++a)
#pragma unroll
      for (int b = 0; b < 4; ++b)
        acc[a][b] += __popcll(av[a].x & bv[b].x) + __popcll(av[a].y & bv[b].y);
  }
#pragma unroll
  for (int a = 0; a < 4; ++a) {        // direct tile [i][j]
    int i = i0 + ty * 4 + a;
    ushort4 wv;
    wv.x = (u16)acc[a][0]; wv.y = (u16)acc[a][1];
    wv.z = (u16)acc[a][2]; wv.w = (u16)acc[a][3];
    *reinterpret_cast<ushort4*>(inter + (size_t)i * NN + j0 + tx * 4) = wv;
  }
  if (bx != by) {
#pragma unroll
    for (int b = 0; b < 4; ++b) {      // mirror tile [j][i]
      int j = j0 + tx * 4 + b;
      ushort4 wv;
      wv.x = (u16)acc[0][b]; wv.y = (u16)acc[1][b];
      wv.z = (u16)acc[2][b]; wv.w = (u16)acc[3][b];
      *reinterpret_cast<ushort4*>(inter + (size_t)j * NN + i0 + ty * 4) = wv;
    }
  }
}

// ===== Boruvka phase A: per-node best outgoing edge (one WAVE per node) =====
// node-local order: (sim desc, partner u asc)  ==  (sim desc, pair-index asc)
__global__ __launch_bounds__(256) void k_scan(const u16* __restrict__ inter,
                                              const u16* __restrict__ deg,
                                              const int* __restrict__ comp,
                                              const int* __restrict__ ncomp,
                                              u64* __restrict__ nkey,
                                              int* __restrict__ nu) {
  if (*ncomp <= 1) return;
  __shared__ int comp_s[NN];   // 16 KiB
  __shared__ u16 deg_s[NN];    // 8 KiB
  int t = threadIdx.x;
  for (int i = t; i < NN / 4; i += 256)
    reinterpret_cast<int4*>(comp_s)[i] = reinterpret_cast<const int4*>(comp)[i];
  for (int i = t; i < NN / 8; i += 256)
    reinterpret_cast<uint4*>(deg_s)[i] = reinterpret_cast<const uint4*>(deg)[i];
  __syncthreads();
  int w = t >> 6, lane = t & 63;
  int v = blockIdx.x * 4 + w;
  int cv = comp_s[v];
  int dv = (int)deg_s[v];
  const u16* row = inter + (size_t)v * NN;
  unsigned bs = 0; int bu = -1;
  for (int it = 0; it < 8; ++it) {
    int ub = it * 512 + lane * 8;
    uint4 pv = *reinterpret_cast<const uint4*>(row + ub);          // 8× u16 inter
    uint4 dg = *reinterpret_cast<const uint4*>(deg_s + ub);        // 8× u16 deg
    int4 c0 = reinterpret_cast<const int4*>(comp_s)[ub >> 2];
    int4 c1 = reinterpret_cast<const int4*>(comp_s)[(ub >> 2) + 1];
    int iv_[8] = { (int)(pv.x & 0xFFFF), (int)(pv.x >> 16), (int)(pv.y & 0xFFFF), (int)(pv.y >> 16),
                   (int)(pv.z & 0xFFFF), (int)(pv.z >> 16), (int)(pv.w & 0xFFFF), (int)(pv.w >> 16) };
    int du_[8] = { (int)(dg.x & 0xFFFF), (int)(dg.x >> 16), (int)(dg.y & 0xFFFF), (int)(dg.y >> 16),
                   (int)(dg.z & 0xFFFF), (int)(dg.z >> 16), (int)(dg.w & 0xFFFF), (int)(dg.w >> 16) };
    int cs_[8] = { c0.x, c0.y, c0.z, c0.w, c1.x, c1.y, c1.z, c1.w };
#pragma unroll
    for (int k = 0; k < 8; ++k) {
      int un = dv + du_[k] - iv_[k];
      float s = (un > 0) ? ((float)iv_[k] / (float)un) : 0.0f;     // exact fp32 div == numpy
      unsigned sb = __float_as_uint(s);
      if (cs_[k] != cv && (bu < 0 || sb > bs)) { bs = sb; bu = ub + k; }
    }
  }
  u64 key = (bu >= 0) ? (((u64)bs << 32) | (u64)(0xFFFFFFFFu - (unsigned)bu)) : 0ull;
#pragma unroll
  for (int off = 32; off > 0; off >>= 1) {                          // wave max-reduce
    unsigned lo = (unsigned)key, hi = (unsigned)(key >> 32);
    unsigned olo = __shfl_xor(lo, off, 64), ohi = __shfl_xor(hi, off, 64);
    u64 o = ((u64)ohi << 32) | (u64)olo;
    if (o > key) key = o;
  }
  if (lane == 0) {
    u64 pk = 0; int u = -1;
    if (key != 0ull) {
      unsigned simb = (unsigned)(key >> 32);
      u = (int)(0xFFFFFFFFu - (unsigned)(key & 0xFFFFFFFFull));
      int i = v < u ? v : u, j = v < u ? u : v;
      unsigned idx = (unsigned)i * (unsigned)(2 * NN - i - 1) / 2u + (unsigned)(j - i - 1);
      pk = ((u64)simb << 24) | (u64)(0xFFFFFFu - idx);              // global pair key
    }
    nkey[v] = pk; nu[v] = u;
  }
}

// ===== Boruvka phase B: component-best, hook, 2-cycle break, jump (LDS) =====
__global__ __launch_bounds__(1024) void k_merge(const u64* __restrict__ nkey,
                                                const int* __restrict__ nu,
                                                int* comp, int* ncomp, int* mstcnt,
                                                u64* mkey, int* mi, int* mj) {
  if (*ncomp <= 1) return;
  __shared__ int parent_s[NN];        // 16 KiB
  __shared__ u64 cbest_s[NN];         // 32 KiB
  __shared__ unsigned char mk_s[NN];  // 4 KiB
  __shared__ int cnt_s, chg_s;
  int t = threadIdx.x;
  for (int c = t; c < NN; c += 1024) { parent_s[c] = c; cbest_s[c] = 0ull; }
  __syncthreads();
  for (int v = t; v < NN; v += 1024) {
    u64 k = nkey[v];
    if (k) atomicMax(&cbest_s[comp[v]], k);
  }
  __syncthreads();
  for (int v = t; v < NN; v += 1024) {
    u64 k = nkey[v];
    if (!k) continue;
    int c = comp[v];
    if (k == cbest_s[c]) {
      int u = nu[v];
      int cu = comp[u];
      bool mutual = (cbest_s[cu] == k);
      if (!mutual || v < u) {
        int slot = atomicAdd(mstcnt, 1);
        mkey[slot] = k; mi[slot] = v; mj[slot] = u;
      }
      parent_s[c] = cu;                // one winner per component
    }
  }
  __syncthreads();
  for (int c = t; c < NN; c += 1024) { // break mutual 2-cycles: keep smaller root
    int pc = parent_s[c];
    if (parent_s[pc] == c && c < pc) parent_s[c] = c;
  }
  __syncthreads();
  for (int it = 0; it < 13; ++it) {    // pointer jumping w/ convergence check
    if (t == 0) chg_s = 0;
    __syncthreads();
    for (int c = t; c < NN; c += 1024) {
      int p1 = parent_s[c], p2 = parent_s[p1];
      if (p1 != p2) { parent_s[c] = p2; chg_s = 1; }
    }
    __syncthreads();
    if (!chg_s) break;
  }
  for (int c = t; c < NN; c += 1024) mk_s[c] = 0;
  if (t == 0) cnt_s = 0;
  __syncthreads();
  for (int v = t; v < NN; v += 1024) {
    int nc = parent_s[comp[v]];
    comp[v] = nc;
    mk_s[nc] = 1;
  }
  __syncthreads();
  int lc = 0;
  for (int c = t; c < NN; c += 1024) lc += mk_s[c];
  atomicAdd(&cnt_s, lc);
  __syncthreads();
  if (t == 0) *ncomp = cnt_s;
}

// ===== finalize: drop 5 smallest MST edges, CC, labels, P =====
__global__ __launch_bounds__(1024) void k_finalize(u64* mkey, const int* __restrict__ mi,
                                                   const int* __restrict__ mj,
                                                   const int* __restrict__ mstcnt,
                                                   int* labels_g, float* invs_g, float* out) {
  __shared__ int p[NN];        // 16 KiB
  __shared__ int rr[NN];       // 16 KiB (root -> rank LUT)
  __shared__ u64 rk[1024];
  __shared__ int rs[1024];
  __shared__ int roots[16];
  __shared__ int rcnt;
  __shared__ int szs[8];
  __shared__ float ivs[8];
  __shared__ int changed;
  int t = threadIdx.x;
  int nm = *mstcnt;            // 4095
  for (int v = t; v < NN; v += 1024) p[v] = v;
  // remove the 5 smallest edges (smallest keys == lowest sim / largest pair-idx)
  for (int pass = 0; pass < NSUP - 1; ++pass) {
    u64 bk = ~0ull; int bs = -1;
    for (int e = t; e < nm; e += 1024) { u64 k = mkey[e]; if (k < bk) { bk = k; bs = e; } }
    rk[t] = bk; rs[t] = bs;
    __syncthreads();
    for (int s = 512; s > 0; s >>= 1) {
      if (t < s && rk[t + s] < rk[t]) { rk[t] = rk[t + s]; rs[t] = rs[t + s]; }
      __syncthreads();
    }
    if (t == 0) mkey[rs[0]] = ~0ull;   // mark removed
    __syncthreads();
  }
  // connected components over kept edges (min-label hook + jump)
  for (int round = 0; round < 64; ++round) {
    if (t == 0) changed = 0;
    __syncthreads();
    for (int e = t; e < nm; e += 1024) {
      if (mkey[e] == ~0ull) continue;
      int a = p[mi[e]], b = p[mj[e]];
      if (a == b) continue;
      int m = a < b ? a : b, M = a < b ? b : a;
      int old = atomicMin(&p[M], m);
      if (old > m) changed = 1;
    }
    __syncthreads();
    for (int rep = 0; rep < 3; ++rep) {
      for (int v = t; v < NN; v += 1024) p[v] = p[p[v]];
      __syncthreads();
    }
    int ch = changed;
    __syncthreads();
    if (!ch) break;
  }
  for (int rep = 0; rep < 13; ++rep) {   // full compression -> p[v] = component min index
    for (int v = t; v < NN; v += 1024) p[v] = p[p[v]];
    __syncthreads();
  }
  if (t == 0) rcnt = 0;
  __syncthreads();
  for (int v = t; v < NN; v += 1024)
    if (p[v] == v) { int s = atomicAdd(&rcnt, 1); if (s < 16) roots[s] = v; }
  __syncthreads();
  if (t == 0) {                           // sort roots asc -> first-occurrence label order
    int c = rcnt > 16 ? 16 : rcnt;
    for (int a = 1; a < c; ++a) {
      int x = roots[a]; int b = a - 1;
      while (b >= 0 && roots[b] > x) { roots[b + 1] = roots[b]; --b; }
      roots[b + 1] = x;
    }
  }
  if (t < 8) szs[t] = 0;
  __syncthreads();
  if (t < rcnt && t < 16) rr[roots[t]] = t;
  __syncthreads();
  for (int v = t; v < NN; v += 1024) {
    int lab = rr[p[v]];
    labels_g[v] = lab;
    atomicAdd(&szs[lab], 1);
  }
  __syncthreads();
  if (t < rcnt && t < 8) {
    float iv = 1.0f / sqrtf((float)szs[t] + 1e-10f);   // bit-matches reference P entries
    ivs[t] = iv; invs_g[t] = iv;
  }
  __syncthreads();
  for (int v = t; v < NN; v += 1024) {                 // P at out+1572, row-major [4096][6]
    int lab = rr[p[v]];
    float* base = out + 1572 + v * 6;
#pragma unroll
    for (int b = 0; b < 6; ++b) base[b] = (b == lab) ? ivs[lab] : 0.0f;
  }
}

// ===== X_coarse = P^T X : label-indexed column sums =====
__global__ __launch_bounds__(256) void k_xcoarse(const float* __restrict__ X,
                                                 const int* __restrict__ labels,
                                                 const float* __restrict__ invs, float* out) {
  __shared__ float acc[6][256];
  __shared__ int labs[64];
  __shared__ float ivl[64];
  int t = threadIdx.x;
#pragma unroll
  for (int m = 0; m < 6; ++m) acc[m][t] = 0.0f;
  if (t < 64) { int v = blockIdx.x * 64 + t; int l = labels[v]; labs[t] = l; ivl[t] = invs[l]; }
  __syncthreads();
  int v0 = blockIdx.x * 64;
  for (int r = 0; r < 64; ++r) {
    float x = X[(size_t)(v0 + r) * 256 + t];
    acc[labs[r]][t] += ivl[r] * x;
  }
  __syncthreads();
#pragma unroll
  for (int m = 0; m < 6; ++m) atomicAdd(&out[m * 256 + t], acc[m][t]);
}

// ===== A_coarse = P^T A P : per-row neighbor-label counts from bit rows =====
__global__ __launch_bounds__(256) void k_acoarse(const u64* __restrict__ bits,
                                                 const int* __restrict__ labels,
                                                 const float* __restrict__ invs, float* out) {
  __shared__ unsigned char labs[NN];   // 4 KiB
  __shared__ float accA[36];
  __shared__ float ivs[8];
  int t = threadIdx.x;
  for (int v = t; v < NN; v += 256) labs[v] = (unsigned char)labels[v];
  if (t < 36) accA[t] = 0.0f;
  if (t < 6) ivs[t] = invs[t];
  __syncthreads();
  int i = blockIdx.x * 256 + t;
  u64 cnt = 0;   // six 10-bit counters
  const u64* row = bits + (size_t)i * NCH;
  for (int c = 0; c < NCH; ++c) {
    u64 w = row[c];
    while (w) {
      int j = (c << 6) + __builtin_ctzll(w);
      w &= w - 1;
      cnt += 1ull << (labs[j] * 10);
    }
  }
  int li = labs[i];
  float fi = ivs[li];
#pragma unroll
  for (int b = 0; b < 6; ++b) {
    float cb = (float)((cnt >> (b * 10)) & 1023ull);
    if (cb != 0.0f) atomicAdd(&accA[li * 6 + b], fi * ivs[b] * cb);
  }
  __syncthreads();
  if (t < 36) atomicAdd(&out[1536 + t], accA[t]);
}

// ============================ launch ============================
extern "C" void kernel_launch(void* const* d_in, const int* in_sizes, int n_in,
                              void* d_out, int out_size, void* d_ws, size_t ws_size,
                              hipStream_t stream) {
  const float* X = (const float*)d_in[0];
  const float* A = (const float*)d_in[1];
  float* out = (float*)d_out;

  char* wp = (char*)d_ws;
  size_t off = 0;
#define WALLOC(ty, name, count) \
  ty* name = (ty*)(wp + off);   \
  off += (((size_t)(count) * sizeof(ty)) + 255) & ~(size_t)255;
  WALLOC(u64, bits, (size_t)NN * NCH)      // 2 MiB
  WALLOC(u16, inter, (size_t)NN * NN)      // 32 MiB
  WALLOC(u16, deg, NN)
  WALLOC(int, comp, NN)
  WALLOC(u64, nkey, NN)
  WALLOC(int, nu, NN)
  WALLOC(u64, mkey, 4352)
  WALLOC(int, mi, 4352)
  WALLOC(int, mj, 4352)
  WALLOC(int, labels, NN)
  WALLOC(float, invs, 8)
  WALLOC(int, ncomp, 1)
  WALLOC(int, mstcnt, 1)
#undef WALLOC
  if (off > ws_size) return;   // workspace too small: leave output zeroed (clean fail)

  k_init<<<64, 256, 0, stream>>>(out, out_size, comp, ncomp, mstcnt);
  k_pack<<<(NN * NCH) / 256, 256, 0, stream>>>(A, bits);
  k_deg<<<NN / 256, 256, 0, stream>>>(bits, deg);
  k_inter<<<4096, 256, 0, stream>>>(bits, inter);
  for (int ph = 0; ph < 12; ++ph) {
    k_scan<<<NN / 4, 256, 0, stream>>>(inter, deg, comp, ncomp, nkey, nu);
    k_merge<<<1, 1024, 0, stream>>>(nkey, nu, comp, ncomp, mstcnt, mkey, mi, mj);
  }
  k_finalize<<<1, 1024, 0, stream>>>(mkey, mi, mj, mstcnt, labels, invs, out);
  k_xcoarse<<<64, 256, 0, stream>>>(X, labels, invs, out);
  k_acoarse<<<16, 256, 0, stream>>>(bits, labels, invs, out);
}